// Round 8
// baseline (90.962 us; speedup 1.0000x reference)
//
#include <hip/hip_runtime.h>
#include <math.h>

#define HW    4096
#define NC    32
#define NB    8
#define TINV  10.0f            // 1/TEMP
#define RWIN  8                // window radius; missed sources need |of|>5.5
#define WDIM  24               // 8 + 2*RWIN
#define RCUT  2.5f             // rect cut; excluded normalized weight < 1e-5
#define LCAP  40               // per-wave survivor cap (structural max 36)

// ws layout: params (float4 per b*HW) then xt (transposed x, [b][j][c])

__global__ __launch_bounds__(256) void prep_kernel(
    const float* __restrict__ x, const float* __restrict__ of,
    float4* __restrict__ params, float* __restrict__ xt)
{
    __shared__ float tile[32][257];
    int b  = blockIdx.x >> 4;
    int j0 = (blockIdx.x & 15) << 8;
    int t  = threadIdx.x;
    int j  = j0 + t;

    float oy = (float)(j >> 6) + of[(b * 2 + 0) * HW + j];
    float ox = (float)(j & 63) + of[(b * 2 + 1) * HW + j];

    // truncated denominators: omitted terms < e^-25 relative
    int cy0 = min(max((int)floorf(oy), 0), 63);
    int cx0 = min(max((int)floorf(ox), 0), 63);
    float Dy = 0.f, Dx = 0.f;
    #pragma unroll
    for (int d = -3; d <= 3; ++d) {
        int iy = cy0 + d, ix = cx0 + d;
        if ((unsigned)iy < 64u) Dy += __expf(-TINV * fabsf(oy - (float)iy));
        if ((unsigned)ix < 64u) Dx += __expf(-TINV * fabsf(ox - (float)ix));
    }
    params[(b << 12) + j] = make_float4(oy, ox, 1.f / Dy, 1.f / Dx);

    // LDS-tiled transpose x[b][c][j] -> xt[b][j][c]; both sides coalesced
    #pragma unroll
    for (int c = 0; c < NC; ++c)
        tile[c][t] = x[((b * NC + c) << 12) + j];
    __syncthreads();
    #pragma unroll
    for (int k = 0; k < NC; ++k) {
        int o  = k * 256 + t;
        int jj = o >> 5, c = o & 31;
        xt[((size_t)((b << 12) + j0 + jj)) * NC + c] = tile[c][jj];
    }
}

// grid: (64 tiles, 2 ch-halves x 4 source-partitions, 8 batches)
// Partition q handles window rows {q, q+4, ..., q+20}; partial sums are
// combined via fp32 atomicAdd into the pre-zeroed output.
__global__ __launch_bounds__(256) void gather_kernel(
    const float4* __restrict__ params, const float4* __restrict__ xt4,
    float* __restrict__ out)
{
    __shared__ float  red[4 * 64 * 17];   // 17408 B
    __shared__ float4 wp[4][LCAP];        //  2560 B
    __shared__ int    sj[4][LCAP];        //   640 B  -> ~20.6 KB

    const int b    = blockIdx.z;
    const int h    = blockIdx.y & 1;      // channel half
    const int q    = blockIdx.y >> 1;     // source partition 0..3
    const int tile = blockIdx.x;
    const int ty0  = (tile >> 3) << 3;
    const int tx0  = (tile & 7) << 3;

    const int tid  = threadIdx.x;
    const int lane = tid & 63;
    const int wv   = __builtin_amdgcn_readfirstlane(tid >> 6);

    const float iy = (float)(ty0 + (lane >> 3));
    const float ix = (float)(tx0 + (lane & 7));

    float acc[16];
    #pragma unroll
    for (int c = 0; c < 16; ++c) acc[c] = 0.f;

    const float4* pb = params + (b << 12);
    const float4* xb = xt4 + (size_t)(b << 12) * 8 + h * 4;  // 16 ch @ half h

    // ---- screen: ONE ballot round; wave wv screens cells wv+4*lane of the
    //      6x24 partition grid (strided -> balanced survivors per wave) ----
    int  ci  = wv + (lane << 2);          // 0..255; valid cells < 144
    bool lv  = (lane < 36);
    int  rr  = ci / 24;
    int  cc  = ci - rr * 24;
    int  row = q + (rr << 2);             // q, q+4, ..., q+20
    int  jy  = ty0 - RWIN + row;
    int  jx  = tx0 - RWIN + cc;
    bool valid = lv && ((unsigned)jy < 64u) && ((unsigned)jx < 64u);
    int  j   = (jy << 6) + jx;
    float4 p = pb[valid ? j : 0];
    float cy = fminf(fmaxf(p.x, 0.f), 63.f);
    float cx = fminf(fmaxf(p.y, 0.f), 63.f);
    float dyr = fmaxf(fmaxf((float)ty0 - cy, cy - ((float)ty0 + 7.f)), 0.f);
    float dxr = fmaxf(fmaxf((float)tx0 - cx, cx - ((float)tx0 + 7.f)), 0.f);
    bool pred = valid && (dyr + dxr < RCUT);

    unsigned long long m = __ballot(pred);
    int cnt = __popcll(m);
    if (pred) {
        int pos = __builtin_amdgcn_mbcnt_hi((unsigned)(m >> 32),
                  __builtin_amdgcn_mbcnt_lo((unsigned)m, 0u));
        wp[wv][pos] = p;
        sj[wv][pos] = j;
    }

    // ---- survivor loop, 2-wide (~12 survivors -> ~6 chain links) ----
    for (int k = 0; k < cnt; k += 2) {
        int i1 = min(k + 1, cnt - 1);
        float4 p0 = wp[wv][k], p1 = wp[wv][i1];
        int j0 = __builtin_amdgcn_readfirstlane(sj[wv][k]);
        int j1 = __builtin_amdgcn_readfirstlane(sj[wv][i1]);

        const float4* x0 = xb + j0 * 8;
        const float4* x1 = xb + j1 * 8;
        float4 A[4], B[4];
        #pragma unroll
        for (int u = 0; u < 4; ++u) A[u] = x0[u];
        #pragma unroll
        for (int u = 0; u < 4; ++u) B[u] = x1[u];

        // per-dim normalize before product (fp32 overflow safety for OOB)
        float g0 = (__expf(-TINV * fabsf(p0.x - iy)) * p0.z)
                 * (__expf(-TINV * fabsf(p0.y - ix)) * p0.w);
        float g1 = (__expf(-TINV * fabsf(p1.x - iy)) * p1.z)
                 * (__expf(-TINV * fabsf(p1.y - ix)) * p1.w);
        g1 = (k + 1 < cnt) ? g1 : 0.f;

        #pragma unroll
        for (int u = 0; u < 4; ++u) {
            acc[4*u+0] = fmaf(g0, A[u].x, acc[4*u+0]);
            acc[4*u+1] = fmaf(g0, A[u].y, acc[4*u+1]);
            acc[4*u+2] = fmaf(g0, A[u].z, acc[4*u+2]);
            acc[4*u+3] = fmaf(g0, A[u].w, acc[4*u+3]);
        }
        #pragma unroll
        for (int u = 0; u < 4; ++u) {
            acc[4*u+0] = fmaf(g1, B[u].x, acc[4*u+0]);
            acc[4*u+1] = fmaf(g1, B[u].y, acc[4*u+1]);
            acc[4*u+2] = fmaf(g1, B[u].z, acc[4*u+2]);
            acc[4*u+3] = fmaf(g1, B[u].w, acc[4*u+3]);
        }
    }

    // ---- cross-wave reduction (stride 17 -> at most 2-way = free) ----
    float* myred = red + (wv * 64 + lane) * 17;
    #pragma unroll
    for (int c = 0; c < 16; ++c) myred[c] = acc[c];
    __syncthreads();

    int c   = tid >> 4;                   // 0..15
    int t16 = tid & 15;
    #pragma unroll
    for (int k = 0; k < 4; ++k) {
        int t = t16 + 16 * k;
        float s = red[(0 * 64 + t) * 17 + c]
                + red[(1 * 64 + t) * 17 + c]
                + red[(2 * 64 + t) * 17 + c]
                + red[(3 * 64 + t) * 17 + c];
        int ch = h * 16 + c;
        atomicAdd(&out[(((b << 5) + ch) << 12)
                       + (ty0 + (t >> 3)) * 64 + (tx0 + (t & 7))], s);
    }
}

extern "C" void kernel_launch(void* const* d_in, const int* in_sizes, int n_in,
                              void* d_out, int out_size, void* d_ws, size_t ws_size,
                              hipStream_t stream) {
    const float* x  = (const float*)d_in[0];   // [8,32,64,64]
    const float* of = (const float*)d_in[1];   // [8,2,64,64]
    float* out = (float*)d_out;                // [8,32,64,64] fp32

    float4* params = (float4*)d_ws;                                    // 512 KB
    float*  xt     = (float*)((char*)d_ws + NB * HW * sizeof(float4)); // 4 MB

    hipMemsetAsync(d_out, 0, (size_t)out_size * sizeof(float), stream);
    prep_kernel<<<dim3(NB * 16), dim3(256), 0, stream>>>(x, of, params, xt);
    gather_kernel<<<dim3(64, 8, NB), dim3(256), 0, stream>>>(params, (const float4*)xt, out);
}